// Round 8
// baseline (42.265 us; speedup 1.0000x reference)
//
#include <hip/hip_runtime.h>
#include <hip/hip_bf16.h>
#include <cstddef>

#define D_IN 512
#define BLOCK 256
#define RPW 8      // rows per wave
#define RPB 32     // rows per block = 4 waves x 8 rows

typedef float f4 __attribute__((ext_vector_type(4)));

// ---------------------------------------------------------------------------
// Gate helpers (pre-kernel only). Template params keep all state[] indices
// compile-time (registers, never scratch — R4 lesson). Wire q = bit (3-q).
// ---------------------------------------------------------------------------
template<int BIT>
__device__ __forceinline__ void applyG(float* sr, float* si,
    float u00r, float u00i, float u01r, float u01i,
    float u10r, float u10i, float u11r, float u11i)
{
#pragma unroll
    for (int m = 0; m < 8; ++m) {
        const int lo = m & (BIT - 1);
        const int i0 = ((m ^ lo) << 1) | lo;
        const int i1 = i0 | BIT;
        float a0r = sr[i0], a0i = si[i0];
        float a1r = sr[i1], a1i = si[i1];
        float n0r = u00r * a0r - u00i * a0i + u01r * a1r - u01i * a1i;
        float n0i = u00r * a0i + u00i * a0r + u01r * a1i + u01i * a1r;
        float n1r = u10r * a0r - u10i * a0i + u11r * a1r - u11i * a1i;
        float n1i = u10r * a0i + u10i * a0r + u11r * a1i + u11i * a1r;
        sr[i0] = n0r; si[i0] = n0i;
        sr[i1] = n1r; si[i1] = n1i;
    }
}

template<int CB, int TB>
__device__ __forceinline__ void applyCNOT(float* sr, float* si)
{
    constexpr int FREE = 15 & ~CB & ~TB;
    constexpr int LO = FREE & (-FREE);
    constexpr int HI = FREE ^ LO;
#pragma unroll
    for (int m = 0; m < 4; ++m) {
        const int idx = CB | ((m & 1) ? LO : 0) | ((m & 2) ? HI : 0);
        const int j = idx | TB;
        float tr = sr[idx]; sr[idx] = sr[j]; sr[j] = tr;
        float ti = si[idx]; si[idx] = si[j]; si[j] = ti;
    }
}

// ---------------------------------------------------------------------------
// Pre-kernel (1 wave): build M (16x16 real symmetric) with out = r^T M r,
// r[idx] = prod_q (bit_q(idx) ? sin(a_q/2) : cos(a_q/2)).
// amp_embedded = (-i)^pop(idx) r[idx]; final = U amp = V r,
// V[:,j] = (-i)^pop(j) U e_j; M = sum_k (1-pop(k)/2)(VR_k VR_k^T + VI_k VI_k^T).
// ---------------------------------------------------------------------------
__global__ void qhead_pre(const float* __restrict__ w, float* __restrict__ M)
{
    __shared__ float VR[16][16], VI[16][16];
    const int lane = threadIdx.x & 63;

    float sr[16], si[16];
#pragma unroll
    for (int i = 0; i < 16; ++i) {
        sr[i] = (i == lane) ? 1.f : 0.f;   // basis e_lane (lanes>=16 all zero)
        si[i] = 0.f;
    }

#define ROTG(g, q)                                                          \
    {                                                                       \
        float phi = w[(g) * 3 + 0], th = w[(g) * 3 + 1],                    \
              om  = w[(g) * 3 + 2];                                         \
        float sn, cs;  sincosf(th * 0.5f, &sn, &cs);                        \
        float sa, ca;  sincosf((phi + om) * 0.5f, &sa, &ca);                \
        float sd, cd;  sincosf((phi - om) * 0.5f, &sd, &cd);                \
        applyG<(1 << (3 - (q)))>(sr, si,  cs * ca, -cs * sa,                \
                                 -sn * cd, -sn * sd,                        \
                                  sn * cd, -sn * sd,                        \
                                  cs * ca,  cs * sa);                       \
    }
    // Layer 0: Rot wires 0..3, CNOT ring range 1
    ROTG(0, 0) ROTG(1, 1) ROTG(2, 2) ROTG(3, 3)
    applyCNOT<8, 4>(sr, si);
    applyCNOT<4, 2>(sr, si);
    applyCNOT<2, 1>(sr, si);
    applyCNOT<1, 8>(sr, si);
    // Layer 1: Rot, CNOT ring range 2
    ROTG(4, 0) ROTG(5, 1) ROTG(6, 2) ROTG(7, 3)
    applyCNOT<8, 2>(sr, si);
    applyCNOT<4, 1>(sr, si);
    applyCNOT<2, 8>(sr, si);
    applyCNOT<1, 4>(sr, si);
#undef ROTG

    if (lane < 16) {
        const int pm = __popc(lane) & 3;   // V[:,j] = (-i)^pop(j) U[:,j]
#pragma unroll
        for (int k = 0; k < 16; ++k) {
            float re = sr[k], im = si[k];
            float vr = (pm == 0) ? re : (pm == 1) ? im
                     : (pm == 2) ? -re : -im;
            float vi = (pm == 0) ? im : (pm == 1) ? -re
                     : (pm == 2) ? -im : re;
            VR[k][lane] = vr;  VI[k][lane] = vi;
        }
    }
    // single wave: in-wave LDS write->read ordering handled by compiler waits
#pragma unroll
    for (int q = 0; q < 4; ++q) {
        const int e = lane + q * 64;
        const int j = e >> 4, b = e & 15;
        float acc = 0.f;
#pragma unroll
        for (int k = 0; k < 16; ++k) {
            const float wk = 1.0f - 0.5f * (float)__popc(k);
            acc += wk * (VR[k][j] * VR[k][b] + VI[k][j] * VI[k][b]);
        }
        M[e] = acc;
    }
}

// ---------------------------------------------------------------------------
// Kernel A (GEMM): one full row per WAVE per pass.
// Lane l owns f4-chunks l and l+64 of the row -> each wave load is a
// contiguous 1KB segment (perfect coalescing). Weights: 8 f4/lane = 32 VGPR.
// Reduction: 3-shuffle distribute (lane ends holding j = lane&3's partial
// over its 4-lane group) + 4 butterfly steps = 7 shuffles/row.
// __launch_bounds__(256,8) pins VGPR <= 64 -> 32 waves/CU (the occupancy the
// 7.2TB/s fill kernels run at; R1-R7 correlate BW ~linearly with waves/CU).
// ---------------------------------------------------------------------------
__global__ __launch_bounds__(BLOCK, 8) void qhead_gemm(
    const float* __restrict__ x,
    const float* __restrict__ fc_w,
    float* __restrict__ dots, int B)
{
    const int t    = threadIdx.x;
    const int lane = t & 63;
    const int wv   = t >> 6;
    const int row0 = blockIdx.x * RPB + wv * RPW;

    const f4* w4 = (const f4*)fc_w;
    f4 wr[4][2];
#pragma unroll
    for (int j = 0; j < 4; ++j) {
        wr[j][0] = w4[j * 128 + lane];
        wr[j][1] = w4[j * 128 + 64 + lane];
    }

    const f4* x4 = (const f4*)x;

#pragma unroll
    for (int p = 0; p < RPW; ++p) {
        int r = row0 + p;
        if (r >= B) r = B - 1;
        const f4* xr = x4 + (size_t)r * 128 + lane;
        f4 a = xr[0];
        f4 b = xr[64];

        float s0 = a[0]*wr[0][0][0] + a[1]*wr[0][0][1]
                 + a[2]*wr[0][0][2] + a[3]*wr[0][0][3]
                 + b[0]*wr[0][1][0] + b[1]*wr[0][1][1]
                 + b[2]*wr[0][1][2] + b[3]*wr[0][1][3];
        float s1 = a[0]*wr[1][0][0] + a[1]*wr[1][0][1]
                 + a[2]*wr[1][0][2] + a[3]*wr[1][0][3]
                 + b[0]*wr[1][1][0] + b[1]*wr[1][1][1]
                 + b[2]*wr[1][1][2] + b[3]*wr[1][1][3];
        float s2 = a[0]*wr[2][0][0] + a[1]*wr[2][0][1]
                 + a[2]*wr[2][0][2] + a[3]*wr[2][0][3]
                 + b[0]*wr[2][1][0] + b[1]*wr[2][1][1]
                 + b[2]*wr[2][1][2] + b[3]*wr[2][1][3];
        float s3 = a[0]*wr[3][0][0] + a[1]*wr[3][0][1]
                 + a[2]*wr[3][0][2] + a[3]*wr[3][0][3]
                 + b[0]*wr[3][1][0] + b[1]*wr[3][1][1]
                 + b[2]*wr[3][1][2] + b[3]*wr[3][1][3];

        // 3-shuffle distribute: lane ends with partial of j = lane&3
        float t01 = (lane & 1) ? s1 : s0;
        float u01 = (lane & 1) ? s0 : s1;
        t01 += __shfl_xor(u01, 1);
        float t23 = (lane & 1) ? s3 : s2;
        float u23 = (lane & 1) ? s2 : s3;
        t23 += __shfl_xor(u23, 1);
        float v = (lane & 2) ? t23 : t01;
        float u = (lane & 2) ? t01 : t23;
        v += __shfl_xor(u, 2);
        // butterfly over the 16 4-lane groups
        v += __shfl_xor(v, 4);
        v += __shfl_xor(v, 8);
        v += __shfl_xor(v, 16);
        v += __shfl_xor(v, 32);

        if (lane < 4) dots[(size_t)r * 4 + lane] = v;
    }
}

// ---------------------------------------------------------------------------
// Kernel B (sim): row-per-thread. Reads 4 raw dots (coalesced f4, L2-hot),
// bias+tanh, 4 sincos, out = r^T M r (M: 1KB global, uniform-address
// broadcast -> scalar loads, L1-hot).
// ---------------------------------------------------------------------------
__global__ __launch_bounds__(256) void qhead_sim(
    const float* __restrict__ dots,
    const float* __restrict__ fc_b,
    const float* __restrict__ Mg,
    float* __restrict__ out, int B)
{
    const int r = blockIdx.x * 256 + threadIdx.x;
    if (r >= B) return;

    f4 d = ((const f4*)dots)[r];
    float c0, c1, c2, c3, s0, s1, s2, s3;
    sincosf(tanhf(d[0] + fc_b[0]) * 0.5f, &s0, &c0);
    sincosf(tanhf(d[1] + fc_b[1]) * 0.5f, &s1, &c1);
    sincosf(tanhf(d[2] + fc_b[2]) * 0.5f, &s2, &c2);
    sincosf(tanhf(d[3] + fc_b[3]) * 0.5f, &s3, &c3);

    // r[idx]: bit3 = wire0 ... bit0 = wire3
    float rA[4] = { c0*c1, c0*s1, s0*c1, s0*s1 };
    float rB[4] = { c2*c3, c2*s3, s2*c3, s2*s3 };
    float rv[16];
#pragma unroll
    for (int uu = 0; uu < 4; ++uu)
#pragma unroll
        for (int vv = 0; vv < 4; ++vv)
            rv[uu * 4 + vv] = rA[uu] * rB[vv];

    const f4* M4 = (const f4*)Mg;
    float res = 0.f;
#pragma unroll
    for (int a = 0; a < 16; ++a) {
        float ta = 0.f;
#pragma unroll
        for (int bq = 0; bq < 4; ++bq) {
            f4 m = M4[a * 4 + bq];
            ta += m[0] * rv[bq * 4 + 0] + m[1] * rv[bq * 4 + 1]
                + m[2] * rv[bq * 4 + 2] + m[3] * rv[bq * 4 + 3];
        }
        res += ta * rv[a];
    }
    out[r] = res;
}

extern "C" void kernel_launch(void* const* d_in, const int* in_sizes, int n_in,
                              void* d_out, int out_size, void* d_ws, size_t ws_size,
                              hipStream_t stream)
{
    const float* x    = (const float*)d_in[0];
    const float* fc_w = (const float*)d_in[1];
    const float* fc_b = (const float*)d_in[2];
    const float* w    = (const float*)d_in[3];
    float* out  = (float*)d_out;
    float* M    = (float*)d_ws;                  // 256 floats
    float* dots = (float*)d_ws + 256;            // 65536*4 floats

    const int B = in_sizes[0] / D_IN;

    qhead_pre<<<1, 64, 0, stream>>>(w, M);
    qhead_gemm<<<(B + RPB - 1) / RPB, BLOCK, 0, stream>>>(x, fc_w, dots, B);
    qhead_sim<<<(B + 255) / 256, 256, 0, stream>>>(dots, fc_b, M, out, B);
}

// Round 9
// 29.925 us; speedup vs baseline: 1.4123x; 1.4123x over previous
//
#include <hip/hip_runtime.h>
#include <hip/hip_bf16.h>
#include <cstddef>

#define D_IN 512
#define BLOCK 256
#define RPB 32     // rows per block = 4 waves x 8 rows

typedef float f4 __attribute__((ext_vector_type(4)));

// ---------------------------------------------------------------------------
// Gate helpers (M-build only). Template params keep all state[] indices
// compile-time (registers, never scratch — R4 lesson). Wire q = bit (3-q).
// ---------------------------------------------------------------------------
template<int BIT>
__device__ __forceinline__ void applyG(float* sr, float* si,
    float u00r, float u00i, float u01r, float u01i,
    float u10r, float u10i, float u11r, float u11i)
{
#pragma unroll
    for (int m = 0; m < 8; ++m) {
        const int lo = m & (BIT - 1);
        const int i0 = ((m ^ lo) << 1) | lo;
        const int i1 = i0 | BIT;
        float a0r = sr[i0], a0i = si[i0];
        float a1r = sr[i1], a1i = si[i1];
        float n0r = u00r * a0r - u00i * a0i + u01r * a1r - u01i * a1i;
        float n0i = u00r * a0i + u00i * a0r + u01r * a1i + u01i * a1r;
        float n1r = u10r * a0r - u10i * a0i + u11r * a1r - u11i * a1i;
        float n1i = u10r * a0i + u10i * a0r + u11r * a1i + u11i * a1r;
        sr[i0] = n0r; si[i0] = n0i;
        sr[i1] = n1r; si[i1] = n1i;
    }
}

template<int CB, int TB>
__device__ __forceinline__ void applyCNOT(float* sr, float* si)
{
    constexpr int FREE = 15 & ~CB & ~TB;
    constexpr int LO = FREE & (-FREE);
    constexpr int HI = FREE ^ LO;
#pragma unroll
    for (int m = 0; m < 4; ++m) {
        const int idx = CB | ((m & 1) ? LO : 0) | ((m & 2) ? HI : 0);
        const int j = idx | TB;
        float tr = sr[idx]; sr[idx] = sr[j]; sr[j] = tr;
        float ti = si[idx]; si[idx] = si[j]; si[j] = ti;
    }
}

// ---------------------------------------------------------------------------
// M-build (runs in gemm's block 0, wave 0): M is 16x16 real symmetric with
// out = r^T M r, r[idx] = prod_q (bit_q(idx) ? sin(a_q/2) : cos(a_q/2)).
// amp_embedded = (-i)^pop(idx) r[idx]; final = U amp = V r,
// V[:,j] = (-i)^pop(j) U e_j; M = sum_k (1-pop(k)/2)(VR_k VR_k^T + VI_k VI_k^T).
// Lane j<16 builds U e_j with compile-time state indices (i==lane selects).
// M is consumed only by the NEXT kernel -> kernel boundary is the sync.
// ---------------------------------------------------------------------------
__device__ void build_M(const float* __restrict__ w, float* __restrict__ M,
                        float VR[16][16], float VI[16][16], int lane)
{
    float sr[16], si[16];
#pragma unroll
    for (int i = 0; i < 16; ++i) {
        sr[i] = (i == lane) ? 1.f : 0.f;   // basis e_lane (lanes>=16 all zero)
        si[i] = 0.f;
    }

#define ROTG(g, q)                                                          \
    {                                                                       \
        float phi = w[(g) * 3 + 0], th = w[(g) * 3 + 1],                    \
              om  = w[(g) * 3 + 2];                                         \
        float sn, cs;  sincosf(th * 0.5f, &sn, &cs);                        \
        float sa, ca;  sincosf((phi + om) * 0.5f, &sa, &ca);                \
        float sd, cd;  sincosf((phi - om) * 0.5f, &sd, &cd);                \
        applyG<(1 << (3 - (q)))>(sr, si,  cs * ca, -cs * sa,                \
                                 -sn * cd, -sn * sd,                        \
                                  sn * cd, -sn * sd,                        \
                                  cs * ca,  cs * sa);                       \
    }
    // Layer 0: Rot wires 0..3, CNOT ring range 1
    ROTG(0, 0) ROTG(1, 1) ROTG(2, 2) ROTG(3, 3)
    applyCNOT<8, 4>(sr, si);
    applyCNOT<4, 2>(sr, si);
    applyCNOT<2, 1>(sr, si);
    applyCNOT<1, 8>(sr, si);
    // Layer 1: Rot, CNOT ring range 2
    ROTG(4, 0) ROTG(5, 1) ROTG(6, 2) ROTG(7, 3)
    applyCNOT<8, 2>(sr, si);
    applyCNOT<4, 1>(sr, si);
    applyCNOT<2, 8>(sr, si);
    applyCNOT<1, 4>(sr, si);
#undef ROTG

    if (lane < 16) {
        const int pm = __popc(lane) & 3;   // V[:,j] = (-i)^pop(j) U[:,j]
#pragma unroll
        for (int k = 0; k < 16; ++k) {
            float re = sr[k], im = si[k];
            float vr = (pm == 0) ? re : (pm == 1) ? im
                     : (pm == 2) ? -re : -im;
            float vi = (pm == 0) ? im : (pm == 1) ? -re
                     : (pm == 2) ? -im : re;
            VR[k][lane] = vr;  VI[k][lane] = vi;
        }
    }
    // single wave: in-wave LDS write->read ordering handled by compiler waits
#pragma unroll
    for (int q = 0; q < 4; ++q) {
        const int e = lane + q * 64;
        const int j = e >> 4, b = e & 15;
        float acc = 0.f;
#pragma unroll
        for (int k = 0; k < 16; ++k) {
            const float wk = 1.0f - 0.5f * (float)__popc(k);
            acc += wk * (VR[k][j] * VR[k][b] + VI[k][j] * VI[k][b]);
        }
        M[e] = acc;
    }
}

// ---------------------------------------------------------------------------
// Kernel A (GEMM) — R3's proven core, unmodified: wave handles 8 rows in 4
// passes of 2 (sub = k-chunk lane of 32, half = row of pair). Loads 4 f4 per
// lane per pass (coalesced 512B segments), weights in 16 f4 regs, butterfly
// allreduce, lanes sub<4 store the 4 dots. No launch_bounds cap beyond block
// size (R8 showed capping VGPR kills load pipelining). Block 0 wave 0
// additionally builds M into ws (hidden among 2048 blocks).
// ---------------------------------------------------------------------------
__global__ __launch_bounds__(BLOCK) void qhead_gemm(
    const float* __restrict__ x,
    const float* __restrict__ fc_w,
    const float* __restrict__ w,
    float* __restrict__ M,
    float* __restrict__ dots, int B)
{
    __shared__ float VR[16][16], VI[16][16];

    const int t    = threadIdx.x;
    const int lane = t & 63;
    const int wv   = t >> 6;
    const int sub  = lane & 31;
    const int half = lane >> 5;
    const int row0 = blockIdx.x * RPB + wv * 8;

    if (blockIdx.x == 0 && wv == 0)
        build_M(w, M, VR, VI, lane);

    // weights: 16 f4 regs per lane (row j, chunk it*32+sub)
    const f4* w4 = (const f4*)fc_w;
    f4 wreg[4][4];
#pragma unroll
    for (int jj = 0; jj < 4; ++jj)
#pragma unroll
        for (int it = 0; it < 4; ++it)
            wreg[jj][it] = w4[jj * 128 + it * 32 + sub];

    const f4* x4 = (const f4*)x;

#pragma unroll
    for (int p = 0; p < 4; ++p) {
        int rp = row0 + p * 2 + half;
        if (rp >= B) rp = B - 1;
        const f4* xr = x4 + (size_t)rp * 128 + sub;

        f4 xv[4];
#pragma unroll
        for (int c = 0; c < 4; ++c) xv[c] = xr[c * 32];

        float s0 = 0.f, s1 = 0.f, s2 = 0.f, s3 = 0.f;
#pragma unroll
        for (int c = 0; c < 4; ++c) {
            f4 v = xv[c];
            s0 += v[0]*wreg[0][c][0] + v[1]*wreg[0][c][1]
                + v[2]*wreg[0][c][2] + v[3]*wreg[0][c][3];
            s1 += v[0]*wreg[1][c][0] + v[1]*wreg[1][c][1]
                + v[2]*wreg[1][c][2] + v[3]*wreg[1][c][3];
            s2 += v[0]*wreg[2][c][0] + v[1]*wreg[2][c][1]
                + v[2]*wreg[2][c][2] + v[3]*wreg[2][c][3];
            s3 += v[0]*wreg[3][c][0] + v[1]*wreg[3][c][1]
                + v[2]*wreg[3][c][2] + v[3]*wreg[3][c][3];
        }

        // butterfly allreduce within the 32-lane group
#pragma unroll
        for (int off = 1; off < 32; off <<= 1) {
            s0 += __shfl_xor(s0, off);
            s1 += __shfl_xor(s1, off);
            s2 += __shfl_xor(s2, off);
            s3 += __shfl_xor(s3, off);
        }

        if (sub < 4) {
            float v = (sub == 0) ? s0 : (sub == 1) ? s1 : (sub == 2) ? s2 : s3;
            dots[(size_t)rp * 4 + sub] = v;
        }
    }
}

// ---------------------------------------------------------------------------
// Kernel B (sim): row-per-thread. 1 coalesced f4 load of raw dots (L2-hot),
// bias+tanh, 4 sincos, out = r^T M r. M address is uniform -> s_load, L1-hot.
// ---------------------------------------------------------------------------
__global__ __launch_bounds__(256) void qhead_sim(
    const float* __restrict__ dots,
    const float* __restrict__ fc_b,
    const float* __restrict__ Mg,
    float* __restrict__ out, int B)
{
    const int r = blockIdx.x * 256 + threadIdx.x;
    if (r >= B) return;

    f4 d = ((const f4*)dots)[r];
    float c0, c1, c2, c3, s0, s1, s2, s3;
    sincosf(tanhf(d[0] + fc_b[0]) * 0.5f, &s0, &c0);
    sincosf(tanhf(d[1] + fc_b[1]) * 0.5f, &s1, &c1);
    sincosf(tanhf(d[2] + fc_b[2]) * 0.5f, &s2, &c2);
    sincosf(tanhf(d[3] + fc_b[3]) * 0.5f, &s3, &c3);

    // r[idx]: bit3 = wire0 ... bit0 = wire3
    float rA[4] = { c0*c1, c0*s1, s0*c1, s0*s1 };
    float rB[4] = { c2*c3, c2*s3, s2*c3, s2*s3 };
    float rv[16];
#pragma unroll
    for (int uu = 0; uu < 4; ++uu)
#pragma unroll
        for (int vv = 0; vv < 4; ++vv)
            rv[uu * 4 + vv] = rA[uu] * rB[vv];

    const f4* M4 = (const f4*)Mg;
    float res = 0.f;
#pragma unroll
    for (int a = 0; a < 16; ++a) {
        float ta = 0.f;
#pragma unroll
        for (int bq = 0; bq < 4; ++bq) {
            f4 m = M4[a * 4 + bq];
            ta += m[0] * rv[bq * 4 + 0] + m[1] * rv[bq * 4 + 1]
                + m[2] * rv[bq * 4 + 2] + m[3] * rv[bq * 4 + 3];
        }
        res += ta * rv[a];
    }
    out[r] = res;
}

extern "C" void kernel_launch(void* const* d_in, const int* in_sizes, int n_in,
                              void* d_out, int out_size, void* d_ws, size_t ws_size,
                              hipStream_t stream)
{
    const float* x    = (const float*)d_in[0];
    const float* fc_w = (const float*)d_in[1];
    const float* fc_b = (const float*)d_in[2];
    const float* w    = (const float*)d_in[3];
    float* out  = (float*)d_out;
    float* M    = (float*)d_ws;                  // 256 floats
    float* dots = (float*)d_ws + 256;            // 65536*4 floats

    const int B = in_sizes[0] / D_IN;

    qhead_gemm<<<(B + RPB - 1) / RPB, BLOCK, 0, stream>>>(
        x, fc_w, w, M, dots, B);
    qhead_sim<<<(B + 255) / 256, 256, 0, stream>>>(dots, fc_b, M, out, B);
}

// Round 10
// 29.919 us; speedup vs baseline: 1.4126x; 1.0002x over previous
//
#include <hip/hip_runtime.h>
#include <hip/hip_bf16.h>
#include <cstddef>

#define D_IN 512
#define BLOCK 256
#define RPW 16     // rows per wave (8 passes x 2 rows)
#define RPB 64     // rows per block = 4 waves x 16 rows

typedef float f4 __attribute__((ext_vector_type(4)));

// ---------------------------------------------------------------------------
// Gate helpers (M-build only). Template params keep all state[] indices
// compile-time (registers, never scratch — R4 lesson). Wire q = bit (3-q).
// ---------------------------------------------------------------------------
template<int BIT>
__device__ __forceinline__ void applyG(float* sr, float* si,
    float u00r, float u00i, float u01r, float u01i,
    float u10r, float u10i, float u11r, float u11i)
{
#pragma unroll
    for (int m = 0; m < 8; ++m) {
        const int lo = m & (BIT - 1);
        const int i0 = ((m ^ lo) << 1) | lo;
        const int i1 = i0 | BIT;
        float a0r = sr[i0], a0i = si[i0];
        float a1r = sr[i1], a1i = si[i1];
        float n0r = u00r * a0r - u00i * a0i + u01r * a1r - u01i * a1i;
        float n0i = u00r * a0i + u00i * a0r + u01r * a1i + u01i * a1r;
        float n1r = u10r * a0r - u10i * a0i + u11r * a1r - u11i * a1i;
        float n1i = u10r * a0i + u10i * a0r + u11r * a1i + u11i * a1r;
        sr[i0] = n0r; si[i0] = n0i;
        sr[i1] = n1r; si[i1] = n1i;
    }
}

template<int CB, int TB>
__device__ __forceinline__ void applyCNOT(float* sr, float* si)
{
    constexpr int FREE = 15 & ~CB & ~TB;
    constexpr int LO = FREE & (-FREE);
    constexpr int HI = FREE ^ LO;
#pragma unroll
    for (int m = 0; m < 4; ++m) {
        const int idx = CB | ((m & 1) ? LO : 0) | ((m & 2) ? HI : 0);
        const int j = idx | TB;
        float tr = sr[idx]; sr[idx] = sr[j]; sr[j] = tr;
        float ti = si[idx]; si[idx] = si[j]; si[j] = ti;
    }
}

// ---------------------------------------------------------------------------
// M-build (runs in gemm's block 0, wave 0): M is 16x16 real symmetric with
// out = r^T M r, r[idx] = prod_q (bit_q(idx) ? sin(a_q/2) : cos(a_q/2)).
// amp_embedded = (-i)^pop(idx) r[idx]; final = U amp = V r,
// V[:,j] = (-i)^pop(j) U e_j; M = sum_k (1-pop(k)/2)(VR_k VR_k^T + VI_k VI_k^T).
// M is consumed only by the NEXT kernel -> kernel boundary is the sync.
// ---------------------------------------------------------------------------
__device__ void build_M(const float* __restrict__ w, float* __restrict__ M,
                        float VR[16][16], float VI[16][16], int lane)
{
    float sr[16], si[16];
#pragma unroll
    for (int i = 0; i < 16; ++i) {
        sr[i] = (i == lane) ? 1.f : 0.f;   // basis e_lane (lanes>=16 all zero)
        si[i] = 0.f;
    }

#define ROTG(g, q)                                                          \
    {                                                                       \
        float phi = w[(g) * 3 + 0], th = w[(g) * 3 + 1],                    \
              om  = w[(g) * 3 + 2];                                         \
        float sn, cs;  sincosf(th * 0.5f, &sn, &cs);                        \
        float sa, ca;  sincosf((phi + om) * 0.5f, &sa, &ca);                \
        float sd, cd;  sincosf((phi - om) * 0.5f, &sd, &cd);                \
        applyG<(1 << (3 - (q)))>(sr, si,  cs * ca, -cs * sa,                \
                                 -sn * cd, -sn * sd,                        \
                                  sn * cd, -sn * sd,                        \
                                  cs * ca,  cs * sa);                       \
    }
    // Layer 0: Rot wires 0..3, CNOT ring range 1
    ROTG(0, 0) ROTG(1, 1) ROTG(2, 2) ROTG(3, 3)
    applyCNOT<8, 4>(sr, si);
    applyCNOT<4, 2>(sr, si);
    applyCNOT<2, 1>(sr, si);
    applyCNOT<1, 8>(sr, si);
    // Layer 1: Rot, CNOT ring range 2
    ROTG(4, 0) ROTG(5, 1) ROTG(6, 2) ROTG(7, 3)
    applyCNOT<8, 2>(sr, si);
    applyCNOT<4, 1>(sr, si);
    applyCNOT<2, 8>(sr, si);
    applyCNOT<1, 4>(sr, si);
#undef ROTG

    if (lane < 16) {
        const int pm = __popc(lane) & 3;   // V[:,j] = (-i)^pop(j) U[:,j]
#pragma unroll
        for (int k = 0; k < 16; ++k) {
            float re = sr[k], im = si[k];
            float vr = (pm == 0) ? re : (pm == 1) ? im
                     : (pm == 2) ? -re : -im;
            float vi = (pm == 0) ? im : (pm == 1) ? -re
                     : (pm == 2) ? -im : re;
            VR[k][lane] = vr;  VI[k][lane] = vi;
        }
    }
    // single wave: in-wave LDS write->read ordering handled by compiler waits
#pragma unroll
    for (int q = 0; q < 4; ++q) {
        const int e = lane + q * 64;
        const int j = e >> 4, b = e & 15;
        float acc = 0.f;
#pragma unroll
        for (int k = 0; k < 16; ++k) {
            const float wk = 1.0f - 0.5f * (float)__popc(k);
            acc += wk * (VR[k][j] * VR[k][b] + VI[k][j] * VI[k][b]);
        }
        M[e] = acc;
    }
}

// ---------------------------------------------------------------------------
// Kernel A (GEMM) — R9's proven core with two surgical changes:
//  (1) 6-shuffle reduce (was 20): distribute s0..s3 to lane&3 via bits 0,1
//      (3 shuffles), then butterfly bits 2,3,4 (3 shuffles). Lane sub<4 ends
//      holding s_sub summed over its 32-lane group -> store unchanged.
//  (2) RPW 16 (was 8): 8 passes/wave -> deeper compiler load pipelining on
//      the same wreg budget; 1024 blocks = exactly 4/CU.
// Lane roles: sub = k-chunk of 32 (coalesced 512B segments), half = row of
// pair. Weights in 16 f4 regs. Block 0 wave 0 also builds M into ws.
// ---------------------------------------------------------------------------
__global__ __launch_bounds__(BLOCK) void qhead_gemm(
    const float* __restrict__ x,
    const float* __restrict__ fc_w,
    const float* __restrict__ w,
    float* __restrict__ M,
    float* __restrict__ dots, int B)
{
    __shared__ float VR[16][16], VI[16][16];

    const int t    = threadIdx.x;
    const int lane = t & 63;
    const int wv   = t >> 6;
    const int sub  = lane & 31;
    const int half = lane >> 5;
    const int row0 = blockIdx.x * RPB + wv * RPW;

    if (blockIdx.x == 0 && wv == 0)
        build_M(w, M, VR, VI, lane);

    // weights: 16 f4 regs per lane (row j, chunk it*32+sub)
    const f4* w4 = (const f4*)fc_w;
    f4 wreg[4][4];
#pragma unroll
    for (int jj = 0; jj < 4; ++jj)
#pragma unroll
        for (int it = 0; it < 4; ++it)
            wreg[jj][it] = w4[jj * 128 + it * 32 + sub];

    const f4* x4 = (const f4*)x;

#pragma unroll
    for (int p = 0; p < RPW / 2; ++p) {
        int rp = row0 + p * 2 + half;
        if (rp >= B) rp = B - 1;
        const f4* xr = x4 + (size_t)rp * 128 + sub;

        f4 xv[4];
#pragma unroll
        for (int c = 0; c < 4; ++c) xv[c] = xr[c * 32];

        float s0 = 0.f, s1 = 0.f, s2 = 0.f, s3 = 0.f;
#pragma unroll
        for (int c = 0; c < 4; ++c) {
            f4 v = xv[c];
            s0 += v[0]*wreg[0][c][0] + v[1]*wreg[0][c][1]
                + v[2]*wreg[0][c][2] + v[3]*wreg[0][c][3];
            s1 += v[0]*wreg[1][c][0] + v[1]*wreg[1][c][1]
                + v[2]*wreg[1][c][2] + v[3]*wreg[1][c][3];
            s2 += v[0]*wreg[2][c][0] + v[1]*wreg[2][c][1]
                + v[2]*wreg[2][c][2] + v[3]*wreg[2][c][3];
            s3 += v[0]*wreg[3][c][0] + v[1]*wreg[3][c][1]
                + v[2]*wreg[3][c][2] + v[3]*wreg[3][c][3];
        }

        // 6-shuffle reduce within the 32-lane group:
        // step 1 (bit 0): pair-sums, even lanes s0/s2, odd lanes s1/s3
        float a01 = (sub & 1) ? s1 : s0;
        float b01 = (sub & 1) ? s0 : s1;
        a01 += __shfl_xor(b01, 1);
        float a23 = (sub & 1) ? s3 : s2;
        float b23 = (sub & 1) ? s2 : s3;
        a23 += __shfl_xor(b23, 1);
        // step 2 (bit 1): lane holds s_{sub&3} over its 4-lane group
        float v = (sub & 2) ? a23 : a01;
        float u = (sub & 2) ? a01 : a23;
        v += __shfl_xor(u, 2);
        // butterfly bits 2..4: s_{sub&3} over all 32 lanes
        v += __shfl_xor(v, 4);
        v += __shfl_xor(v, 8);
        v += __shfl_xor(v, 16);

        if (sub < 4) dots[(size_t)rp * 4 + sub] = v;
    }
}

// ---------------------------------------------------------------------------
// Kernel B (sim): row-per-thread. 1 coalesced f4 load of raw dots (L2-hot),
// bias+tanh, 4 sincos, out = r^T M r. M address is uniform -> s_load, L1-hot.
// ---------------------------------------------------------------------------
__global__ __launch_bounds__(256) void qhead_sim(
    const float* __restrict__ dots,
    const float* __restrict__ fc_b,
    const float* __restrict__ Mg,
    float* __restrict__ out, int B)
{
    const int r = blockIdx.x * 256 + threadIdx.x;
    if (r >= B) return;

    f4 d = ((const f4*)dots)[r];
    float c0, c1, c2, c3, s0, s1, s2, s3;
    sincosf(tanhf(d[0] + fc_b[0]) * 0.5f, &s0, &c0);
    sincosf(tanhf(d[1] + fc_b[1]) * 0.5f, &s1, &c1);
    sincosf(tanhf(d[2] + fc_b[2]) * 0.5f, &s2, &c2);
    sincosf(tanhf(d[3] + fc_b[3]) * 0.5f, &s3, &c3);

    // r[idx]: bit3 = wire0 ... bit0 = wire3
    float rA[4] = { c0*c1, c0*s1, s0*c1, s0*s1 };
    float rB[4] = { c2*c3, c2*s3, s2*c3, s2*s3 };
    float rv[16];
#pragma unroll
    for (int uu = 0; uu < 4; ++uu)
#pragma unroll
        for (int vv = 0; vv < 4; ++vv)
            rv[uu * 4 + vv] = rA[uu] * rB[vv];

    const f4* M4 = (const f4*)Mg;
    float res = 0.f;
#pragma unroll
    for (int a = 0; a < 16; ++a) {
        float ta = 0.f;
#pragma unroll
        for (int bq = 0; bq < 4; ++bq) {
            f4 m = M4[a * 4 + bq];
            ta += m[0] * rv[bq * 4 + 0] + m[1] * rv[bq * 4 + 1]
                + m[2] * rv[bq * 4 + 2] + m[3] * rv[bq * 4 + 3];
        }
        res += ta * rv[a];
    }
    out[r] = res;
}

extern "C" void kernel_launch(void* const* d_in, const int* in_sizes, int n_in,
                              void* d_out, int out_size, void* d_ws, size_t ws_size,
                              hipStream_t stream)
{
    const float* x    = (const float*)d_in[0];
    const float* fc_w = (const float*)d_in[1];
    const float* fc_b = (const float*)d_in[2];
    const float* w    = (const float*)d_in[3];
    float* out  = (float*)d_out;
    float* M    = (float*)d_ws;                  // 256 floats
    float* dots = (float*)d_ws + 256;            // 65536*4 floats

    const int B = in_sizes[0] / D_IN;

    qhead_gemm<<<(B + RPB - 1) / RPB, BLOCK, 0, stream>>>(
        x, fc_w, w, M, dots, B);
    qhead_sim<<<(B + 255) / 256, 256, 0, stream>>>(dots, fc_b, M, out, B);
}